// Round 2
// baseline (11115.327 us; speedup 1.0000x reference)
//
#include <hip/hip_runtime.h>

typedef unsigned short u16;
typedef unsigned int   u32;
typedef short s16x4 __attribute__((ext_vector_type(4)));
typedef short s16x8 __attribute__((ext_vector_type(8)));
typedef float f32x4 __attribute__((ext_vector_type(4)));
typedef u32   u32x2 __attribute__((ext_vector_type(2)));
typedef u32   u32x4 __attribute__((ext_vector_type(4)));

#define GK 1024   // all GEMMs here have K=1024

__device__ inline u16 f2bf(float f) {
    u32 u = __builtin_bit_cast(u32, f);
    u += 0x7FFFu + ((u >> 16) & 1u);
    return (u16)(u >> 16);
}
__device__ inline float bf2f(u16 h) {
    return __builtin_bit_cast(float, (u32)h << 16);
}
__device__ inline u16 f2h(float f) {
    _Float16 h = (_Float16)f;
    return __builtin_bit_cast(u16, h);
}
__device__ inline float h2f(u16 u) {
    return (float)__builtin_bit_cast(_Float16, u);
}
__device__ inline float fast_sigmoid(float x) {
    return __builtin_amdgcn_rcpf(1.f + __expf(-x));
}
__device__ inline float fast_tanh(float x) {
    // 1 - 2/(exp(2x)+1); exact at +-inf saturation
    return 1.f - 2.f * __builtin_amdgcn_rcpf(1.f + __expf(2.f * x));
}
__device__ inline f32x4 mfma16(s16x8 a, s16x8 b, f32x4 c) {
    return __builtin_amdgcn_mfma_f32_16x16x32_bf16(a, b, c, 0, 0, 0);
}

// ---------------- f32 -> bf16 convert (x) ----------------
__global__ void k_f2bf(const float* __restrict__ in, u16* __restrict__ out, int n) {
    int i = (blockIdx.x * 256 + threadIdx.x) * 4;
    if (i < n) {
        float4 v = *(const float4*)(in + i);
        ushort4 o;
        o.x = f2bf(v.x); o.y = f2bf(v.y); o.z = f2bf(v.z); o.w = f2bf(v.w);
        *(ushort4*)(out + i) = o;
    }
}

// ---------------- transpose + convert: out[c][r] = bf16(in[r][c]) ----------------
__global__ void k_transpose_bf(const float* __restrict__ in, u16* __restrict__ out,
                               int R, int C) {
    __shared__ float tile[32][33];
    int tid = threadIdx.x;
    int xs = (tid & 7) * 4;
    int y  = tid >> 3;
    int r0 = blockIdx.y * 32, c0 = blockIdx.x * 32;
    float4 v = *(const float4*)(in + (size_t)(r0 + y) * C + c0 + xs);
    tile[y][xs + 0] = v.x; tile[y][xs + 1] = v.y;
    tile[y][xs + 2] = v.z; tile[y][xs + 3] = v.w;
    __syncthreads();
    ushort4 o;
    o.x = f2bf(tile[xs + 0][y]); o.y = f2bf(tile[xs + 1][y]);
    o.z = f2bf(tile[xs + 2][y]); o.w = f2bf(tile[xs + 3][y]);
    *(ushort4*)(out + (size_t)(c0 + y) * R + r0 + xs) = o;
}

// ---------------- bf16 GEMM: C[m][n] = sum_k A[m][k] * BT[n][k] (+epilogue) ----------------
// MODE 0: xproj: write fp16 to Cb at row (m&511)*32 + (m>>9)  (i.e. [T][B][4096]), add bias[n]
// MODE 1: heads: n<256 -> softplus(acc+bias[n]) + ymin[n] -> Cf[m*256+n]
//                n>=256 -> acc + b2[n-256] -> Cf[4194304 + m*256 + n-256]
template<int MODE>
__launch_bounds__(256, 2)
__global__ void k_gemm(const u16* __restrict__ A, const u16* __restrict__ BT,
                       const float* __restrict__ bias,
                       u16* __restrict__ Cb, float* __restrict__ Cf,
                       const float* __restrict__ b2, const float* __restrict__ ymin,
                       int gridN) {
    int bid = blockIdx.x;
    int m0 = (bid / gridN) * 128, n0 = (bid % gridN) * 128;
    __shared__ u16 As[128 * 40];
    __shared__ u16 Bs[128 * 40];
    int tid = threadIdx.x;
    int lane = tid & 63, w = tid >> 6;
    int wr = w >> 1, wc = w & 1;
    int rr = lane & 15, r16 = lane >> 4;
    f32x4 acc[4][4] = {};
    for (int kt = 0; kt < GK / 32; ++kt) {
        int k0 = kt * 32;
#pragma unroll
        for (int it = 0; it < 2; ++it) {
            int idx = it * 256 + tid;
            int row = idx >> 2, ch = idx & 3;
            *(u32x4*)(&As[row * 40 + ch * 8]) =
                *(const u32x4*)(A + (size_t)(m0 + row) * GK + k0 + ch * 8);
            *(u32x4*)(&Bs[row * 40 + ch * 8]) =
                *(const u32x4*)(BT + (size_t)(n0 + row) * GK + k0 + ch * 8);
        }
        __syncthreads();
        s16x8 af[4], bfr[4];
#pragma unroll
        for (int i = 0; i < 4; ++i) {
            int abase = (wr * 64 + i * 16 + rr) * 40 + r16 * 4;
            s16x4 lo = *(const s16x4*)(&As[abase]);
            s16x4 hi = *(const s16x4*)(&As[abase + 16]);
            af[i] = __builtin_shufflevector(lo, hi, 0, 1, 2, 3, 4, 5, 6, 7);
            int bbase = (wc * 64 + i * 16 + rr) * 40 + r16 * 4;
            s16x4 blo = *(const s16x4*)(&Bs[bbase]);
            s16x4 bhi = *(const s16x4*)(&Bs[bbase + 16]);
            bfr[i] = __builtin_shufflevector(blo, bhi, 0, 1, 2, 3, 4, 5, 6, 7);
        }
#pragma unroll
        for (int i = 0; i < 4; ++i)
#pragma unroll
            for (int j = 0; j < 4; ++j)
                acc[i][j] = mfma16(af[i], bfr[j], acc[i][j]);
        __syncthreads();
    }
#pragma unroll
    for (int i = 0; i < 4; ++i) {
#pragma unroll
        for (int j = 0; j < 4; ++j) {
#pragma unroll
            for (int r = 0; r < 4; ++r) {
                int m = m0 + wr * 64 + i * 16 + r16 * 4 + r;
                int n = n0 + wc * 64 + j * 16 + rr;
                float v = acc[i][j][r];
                if (MODE == 0) {
                    v += bias[n];
                    int orow = (m & 511) * 32 + (m >> 9);
                    Cb[(size_t)orow * 4096 + n] = f2h(v);   // fp16 xproj
                } else {
                    if (n < 256) {
                        v += bias[n];
                        float sp = fmaxf(v, 0.f) + log1pf(expf(-fabsf(v)));
                        Cf[(size_t)m * 256 + n] = sp + ymin[n];
                    } else {
                        v += b2[n - 256];
                        Cf[4194304 + (size_t)m * 256 + (n - 256)] = v;
                    }
                }
            }
        }
    }
}

// ---------------- persistent LSTM recurrence ----------------
// 128 blocks x 256 threads. Block owns 8 hidden units (32 gate columns).
// WhT: [4096][1024] bf16 (transposed Wh).  xproj: [(t*32+b)*4096 + col] fp16.
// hbuf: [2][32][1024] bf16 (double-buffered h broadcast). hout: [b][t][u] bf16.
__launch_bounds__(256, 1)
__global__ void k_lstm(const u16* __restrict__ WhT, const u16* __restrict__ xproj,
                       u16* __restrict__ hbuf, u16* __restrict__ hout,
                       u32* __restrict__ flags) {
    __shared__ u16 hA[32768];            // [mt(2)][kt(32)][lane(64)][8] frag-packed, lane^kt swizzle
    __shared__ float red[4][64][16];     // per-wave partial accumulators
    int tid = threadIdx.x, blk = blockIdx.x;
    int lane = tid & 63, w = tid >> 6;
    int u0 = blk * 8;
    int rr = lane & 15, r16 = lane >> 4;

    // ---- load Wh B-fragments into registers (once) ----
    s16x8 bb[2][8];
#pragma unroll
    for (int q = 0; q < 8; ++q) {
        int kt = w * 8 + q;
#pragma unroll
        for (int nt = 0; nt < 2; ++nt) {
            int col = nt * 16 + rr;                      // local col 0..31 = [i|f|g|o] x 8 units
            int cg  = (col >> 3) * 1024 + u0 + (col & 7);
            const u16* p = WhT + (size_t)cg * GK + kt * 32 + r16 * 4;
            s16x4 lo = *(const s16x4*)p;
            s16x4 hi = *(const s16x4*)(p + 16);
            bb[nt][q] = __builtin_shufflevector(lo, hi, 0, 1, 2, 3, 4, 5, 6, 7);
        }
    }
    float c_reg = 0.f;
    int b_ = tid >> 3, u_ = tid & 7;
    int ep_lane_base = 16 * ((b_ >> 2) & 3);
    int ep_reg = b_ & 3;
    int ep_mt  = b_ >> 4;

    for (int t = 0; t < 512; ++t) {
        // ---- stage h_{t-1} into frag-packed LDS ----
        const u16* hsrc = hbuf + ((t + 1) & 1) * 32768;
#pragma unroll
        for (int i = 0; i < 16; ++i) {
            int cid = i * 256 + tid;
            int m = cid >> 7, c = cid & 127;
            u32x4 v = *(const u32x4*)(hsrc + m * 1024 + c * 8);
            int kt  = c >> 2;
            int lh1 = (c & 1) * 2;
            int jh  = (c >> 1) & 1;
            int mt  = m >> 4;
            int l1  = ((m & 15) ^ (kt & 15)) + 16 * lh1;
            int e1  = ((mt * 32 + kt) * 64 + l1) * 8 + jh * 4;
            u32x2 wlo; wlo.x = v.x; wlo.y = v.y;
            u32x2 whi; whi.x = v.z; whi.y = v.w;
            *(u32x2*)(&hA[e1])       = wlo;
            *(u32x2*)(&hA[e1 + 128]) = whi;   // lane' + 16
        }
        __syncthreads();
        // ---- MFMA: K-split across 4 waves ----
        f32x4 acc00 = {}, acc01 = {}, acc10 = {}, acc11 = {};
#pragma unroll
        for (int q = 0; q < 8; ++q) {
            int kt = w * 8 + q;
            int lsw = ((lane & 15) ^ (kt & 15)) | (lane & 48);
            s16x8 a0 = *(const s16x8*)(&hA[((0 * 32 + kt) * 64 + lsw) * 8]);
            s16x8 a1 = *(const s16x8*)(&hA[((1 * 32 + kt) * 64 + lsw) * 8]);
            acc00 = mfma16(a0, bb[0][q], acc00);
            acc01 = mfma16(a0, bb[1][q], acc01);
            acc10 = mfma16(a1, bb[0][q], acc10);
            acc11 = mfma16(a1, bb[1][q], acc11);
        }
        *(f32x4*)(&red[w][lane][0])  = acc00;
        *(f32x4*)(&red[w][lane][4])  = acc01;
        *(f32x4*)(&red[w][lane][8])  = acc10;
        *(f32x4*)(&red[w][lane][12]) = acc11;
        __syncthreads();
        // ---- epilogue: thread = (batch b_, unit u_) ----
        float g4[4];
#pragma unroll
        for (int gate = 0; gate < 4; ++gate) {
            int col = gate * 8 + u_;
            int nt = col >> 4, cn = col & 15;
            int lx = cn + ep_lane_base;
            int ridx = (ep_mt * 2 + nt) * 4 + ep_reg;
            float s = red[0][lx][ridx] + red[1][lx][ridx] +
                      red[2][lx][ridx] + red[3][lx][ridx];
            s += h2f(xproj[(size_t)(t * 32 + b_) * 4096 + gate * 1024 + u0 + u_]);
            g4[gate] = s;
        }
        float ig = fast_sigmoid(g4[0]);
        float fg = fast_sigmoid(g4[1]);
        float gg = fast_tanh(g4[2]);
        float og = fast_sigmoid(g4[3]);
        c_reg = fg * c_reg + ig * gg;
        float h = og * fast_tanh(c_reg);
        u16 hb = f2bf(h);
        hbuf[(t & 1) * 32768 + b_ * 1024 + u0 + u_] = hb;
        hout[(size_t)b_ * 524288 + (size_t)t * 1024 + u0 + u_] = hb;
        // ---- grid sync (flag array, all 128 blocks co-resident) ----
        __syncthreads();
        if (w == 0) {
            if (tid == 0)
                __hip_atomic_store(&flags[blk], (u32)(t + 1), __ATOMIC_RELEASE,
                                   __HIP_MEMORY_SCOPE_AGENT);
            u32 tgt = (u32)(t + 1);
            while (true) {
                u32 v0 = __hip_atomic_load(&flags[lane], __ATOMIC_RELAXED,
                                           __HIP_MEMORY_SCOPE_AGENT);
                u32 v1 = __hip_atomic_load(&flags[64 + lane], __ATOMIC_RELAXED,
                                           __HIP_MEMORY_SCOPE_AGENT);
                if (__all((v0 >= tgt) && (v1 >= tgt))) break;
                __builtin_amdgcn_s_sleep(1);
            }
            __threadfence();
        }
        __syncthreads();
    }
}

extern "C" void kernel_launch(void* const* d_in, const int* in_sizes, int n_in,
                              void* d_out, int out_size, void* d_ws, size_t ws_size,
                              hipStream_t stream) {
    const float* x   = (const float*)d_in[0];
    const float* Wx  = (const float*)d_in[1];
    const float* Wh  = (const float*)d_in[2];
    const float* b   = (const float*)d_in[3];
    const float* Wmu = (const float*)d_in[4];
    const float* bmu = (const float*)d_in[5];
    const float* Wls = (const float*)d_in[6];
    const float* bls = (const float*)d_in[7];
    const float* ym  = (const float*)d_in[8];
    float* out = (float*)d_out;

    // workspace layout: 236,061,184 B total (fits 256 MiB)
    char* ws = (char*)d_ws;
    u16* xbf   = (u16*)(ws);                    // 33,554,432 B  (aliased: h1 after gemm0)
    u16* h1    = xbf;                           //   (same region; xbf dead after gemm0)
    u16* wxT   = (u16*)(ws + 33554432);         // 16,777,216 B  [2][4096][1024]
    u16* whT   = (u16*)(ws + 50331648);         // 16,777,216 B
    u16* whdT  = (u16*)(ws + 67108864);         //  1,048,576 B  [512][1024]
    u16* xproj = (u16*)(ws + 68157440);         // 134,217,728 B [512][32][4096] fp16
    u16* h2    = (u16*)(ws + 202375168);        // 33,554,432 B
    u16* hbuf  = (u16*)(ws + 235929600);        //    131,072 B
    u32* flags = (u32*)(ws + 236060672);        //        512 B

    // prep: conversions / transposes
    k_f2bf<<<16384, 256, 0, stream>>>(x, xbf, 16777216);
    dim3 tg(128, 32);
    k_transpose_bf<<<tg, 256, 0, stream>>>(Wx,           wxT,           1024, 4096);
    k_transpose_bf<<<tg, 256, 0, stream>>>(Wx + 4194304, wxT + 4194304, 1024, 4096);
    k_transpose_bf<<<tg, 256, 0, stream>>>(Wh,           whT,           1024, 4096);
    k_transpose_bf<<<tg, 256, 0, stream>>>(Wh + 4194304, whT + 4194304, 1024, 4096);
    dim3 hg(8, 32);
    k_transpose_bf<<<hg, 256, 0, stream>>>(Wmu, whdT,          1024, 256);
    k_transpose_bf<<<hg, 256, 0, stream>>>(Wls, whdT + 262144, 1024, 256);

    // layer 0
    k_gemm<0><<<4096, 256, 0, stream>>>(xbf, wxT, b, xproj, nullptr, nullptr, nullptr, 32);
    hipMemsetAsync(hbuf, 0, 131072 + 512, stream);
    k_lstm<<<128, 256, 0, stream>>>(whT, xproj, hbuf, h1, flags);
    // layer 1
    k_gemm<0><<<4096, 256, 0, stream>>>(h1, wxT + 4194304, b + 4096, xproj,
                                        nullptr, nullptr, nullptr, 32);
    hipMemsetAsync(hbuf, 0, 131072 + 512, stream);
    k_lstm<<<128, 256, 0, stream>>>(whT + 4194304, xproj, hbuf, h2, flags);
    // heads (mu || log_sigma)
    k_gemm<1><<<512, 256, 0, stream>>>(h2, whdT, bmu, nullptr, out, bls, ym, 4);
}